// Round 3
// baseline (342.960 us; speedup 1.0000x reference)
//
#include <hip/hip_runtime.h>
#include <hip/hip_bf16.h>

// Grapher block: RepCPE(dw7x7+res) -> fc1+BN -> MRConv4d(K=2) -> gc(2C->C)+BN+GELU -> fc2+BN
// B=32, C=192, H=W=56. d_in/d_out are FLOAT32; intermediates bf16.
//
//   fold:   BN-fold weights -> W1f[192][192], Wgf[192][384], W2f[192][192] (bf16), biases fp32
//   dwconv: (b, 32ch, 8rows) blocks, bf16 LDS, b64 reads, residual folded into center tap
//           -> y0 PIXEL-MAJOR bf16 [b*3136+hw][192]
//   gemm1:  y1 = y0 * W1f^T        (BM=128, 1 K-chunk, D[p][o])    -> y1 bf16 pm (d_out)
//   xj:     max-relative 4 rolls   -> xjb bf16 pm
//   gemm2:  y2 = GELU([y1|xj]*Wgf) (2 K-chunks, D[p][o])           -> y2 bf16 pm (y0 buf)
//   gemm3:  out = y2 * W2f^T       (swapped ops, D[o][p])          -> d_out f32 channel-major

#define CC   192
#define HW   3136
#define NB   32

using short8 = __attribute__((ext_vector_type(8))) short;
using f32x4  = __attribute__((ext_vector_type(4))) float;

__device__ __forceinline__ float bf2f(short s) {
  union { unsigned u; float f; } x; x.u = ((unsigned)(unsigned short)s) << 16; return x.f;
}
__device__ __forceinline__ short f2bf(float f) {
  __hip_bfloat16 h = __float2bfloat16(f);
  return *reinterpret_cast<short*>(&h);
}
__device__ __forceinline__ float geluf(float v) {
  return 0.5f * v * (1.0f + erff(v * 0.70710678118654752f));
}

// ---------------- fold: BN into weights/bias ----------------
__global__ void __launch_bounds__(256) fold_kernel(
    const float* __restrict__ fc1_w, const float* __restrict__ fc1_b,
    const float* __restrict__ bn1_g, const float* __restrict__ bn1_b,
    const float* __restrict__ bn1_m, const float* __restrict__ bn1_v,
    const float* __restrict__ gc_w,  const float* __restrict__ gc_b,
    const float* __restrict__ bng_g, const float* __restrict__ bng_b,
    const float* __restrict__ bng_m, const float* __restrict__ bng_v,
    const float* __restrict__ fc2_w, const float* __restrict__ fc2_b,
    const float* __restrict__ bn2_g, const float* __restrict__ bn2_b,
    const float* __restrict__ bn2_m, const float* __restrict__ bn2_v,
    __hip_bfloat16* __restrict__ W1f, __hip_bfloat16* __restrict__ Wgf, __hip_bfloat16* __restrict__ W2f,
    float* __restrict__ b1f, float* __restrict__ bgf, float* __restrict__ b2f) {
  int gt = blockIdx.x * 256 + threadIdx.x;
  if (gt < 3 * CC) {
    int which = gt / CC, o = gt - which * CC;
    const float *G, *Bt, *M, *V, *Bi; float* dst;
    if (which == 0)      { G = bn1_g; Bt = bn1_b; M = bn1_m; V = bn1_v; Bi = fc1_b; dst = b1f; }
    else if (which == 1) { G = bng_g; Bt = bng_b; M = bng_m; V = bng_v; Bi = gc_b;  dst = bgf; }
    else                 { G = bn2_g; Bt = bn2_b; M = bn2_m; V = bn2_v; Bi = fc2_b; dst = b2f; }
    float inv = G[o] * rsqrtf(V[o] + 1e-5f);
    dst[o] = Bi[o] * inv + Bt[o] - M[o] * inv;
  }
  int i = gt;
  if (i < CC * CC) {
    int o = i / CC;
    float inv = bn1_g[o] * rsqrtf(bn1_v[o] + 1e-5f);
    W1f[i] = __float2bfloat16(fc1_w[i] * inv);
  } else if (i < CC * CC + CC * 2 * CC) {
    int j = i - CC * CC; int o = j / (2 * CC);
    float inv = bng_g[o] * rsqrtf(bng_v[o] + 1e-5f);
    Wgf[j] = __float2bfloat16(gc_w[j] * inv);
  } else if (i < CC * CC * 4) {
    int j = i - CC * CC * 3; int o = j / CC;
    float inv = bn2_g[o] * rsqrtf(bn2_v[o] + 1e-5f);
    W2f[j] = __float2bfloat16(fc2_w[j] * inv);
  }
}

// ---------------- dw 7x7 + bias + residual -> PIXEL-MAJOR bf16 ----------------
// block: (b, cg of 32 ch, rs of 8 rows). LDS in_t[14 rows][32 c][68 cols] bf16,
// cols 4..59 = w 0..55 (zero halo). Thread: c = t&31; items (c, wq), 4 out cols x 8 rows.
__global__ void __launch_bounds__(256) dwconv_kernel(
    const float* __restrict__ x, const float* __restrict__ cw,
    const float* __restrict__ cb, __hip_bfloat16* __restrict__ y0pm) {
  __shared__ short in_t[14 * 32 * 68];
  __shared__ float wt[32 * 49];
  const int t = threadIdx.x;
  int bb = blockIdx.x;
  const int rs = bb % 7; bb /= 7;
  const int cg = bb % 6; bb /= 6;
  const int b  = bb;
  const int h0 = rs * 8;

  for (int i = t; i < 14 * 32 * 68 / 2; i += 256) ((int*)in_t)[i] = 0;
  for (int i = t; i < 32 * 49; i += 256) wt[i] = cw[(cg * 32 + i / 49) * 49 + (i % 49)];
  __syncthreads();
  for (int it = t; it < 32 * 14 * 14; it += 256) {
    int c = it / 196, rem = it - c * 196, rr = rem / 14, w4 = (rem - rr * 14) * 4;
    int gh = h0 - 3 + rr;
    if (gh >= 0 && gh < 56) {
      float4 v = *(const float4*)(x + (((size_t)(b * CC + cg * 32 + c) * 56 + gh) * 56 + w4));
      short* d = &in_t[rr * 2176 + c * 68 + 4 + w4];
      d[0] = f2bf(v.x); d[1] = f2bf(v.y); d[2] = f2bf(v.z); d[3] = f2bf(v.w);
    }
  }
  __syncthreads();

  const int c = t & 31;
  float wreg[49];
#pragma unroll
  for (int i = 0; i < 49; ++i) wreg[i] = wt[c * 49 + i];
  wreg[24] += 1.0f;                      // residual = center tap + 1
  const float bias = cb[cg * 32 + c];

  for (int it = t; it < 448; it += 256) {
    int wq = it >> 5;                    // it&31 == c
    int wc = wq * 4;
    float acc[8][4] = {};
#pragma unroll
    for (int rr = 0; rr < 14; ++rr) {
      const short* rp = &in_t[rr * 2176 + c * 68 + wc];  // 8B-aligned
      int2 d0 = *(const int2*)(rp);
      int2 d1 = *(const int2*)(rp + 4);
      int2 d2 = *(const int2*)(rp + 8);
      int dw[6] = { d0.x, d0.y, d1.x, d1.y, d2.x, d2.y };
      float v[12];
#pragma unroll
      for (int q = 0; q < 6; ++q) {
        union { int i; float f; } lo, hi;
        lo.i = dw[q] << 16; hi.i = dw[q] & 0xffff0000;
        v[q * 2] = lo.f; v[q * 2 + 1] = hi.f;
      }
#pragma unroll
      for (int r = 0; r < 8; ++r) {
        if (rr - r >= 0 && rr - r < 7) {
          const int kh = rr - r;
#pragma unroll
          for (int kw = 0; kw < 7; ++kw) {
            float wv = wreg[kh * 7 + kw];
#pragma unroll
            for (int ccx = 0; ccx < 4; ++ccx)
              acc[r][ccx] = fmaf(wv, v[ccx + 1 + kw], acc[r][ccx]);
          }
        }
      }
    }
    size_t obase = ((size_t)b * HW + (size_t)h0 * 56 + wc) * CC + cg * 32 + c;
#pragma unroll
    for (int r = 0; r < 8; ++r)
#pragma unroll
      for (int ccx = 0; ccx < 4; ++ccx)
        ((short*)y0pm)[obase + ((size_t)r * 56 + ccx) * CC] = f2bf(acc[r][ccx] + bias);
  }
}

// ---------------- MRConv4d: x_j = relu(max(4 rolled) - center), pixel-major bf16 ----------------
__global__ void __launch_bounds__(256) xj_kernel(const __hip_bfloat16* __restrict__ y1,
                                                 __hip_bfloat16* __restrict__ xjb) {
  const int total = NB * HW * 24;
  const short* base = (const short*)y1;
  for (int idx = blockIdx.x * 256 + threadIdx.x; idx < total; idx += gridDim.x * 256) {
    int cg = idx % 24;
    int row = idx / 24;
    int b = row / HW, hw = row - b * HW;
    int h = hw / 56, wv = hw - h * 56;
    int hp = (h >= 54) ? h - 54 : h + 2;
    int hm = (h < 2) ? h + 54 : h - 2;
    int wpp = (wv >= 54) ? wv - 54 : wv + 2;
    int wmm = (wv < 2) ? wv + 54 : wv - 2;
    size_t rb = (size_t)b * HW;
    int co = cg * 8;
    short8 c0 = *(const short8*)(base + (rb + hw) * CC + co);
    short8 n1 = *(const short8*)(base + (rb + hp * 56 + wv) * CC + co);
    short8 n2 = *(const short8*)(base + (rb + hm * 56 + wv) * CC + co);
    short8 n3 = *(const short8*)(base + (rb + h * 56 + wpp) * CC + co);
    short8 n4 = *(const short8*)(base + (rb + h * 56 + wmm) * CC + co);
    short8 res;
#pragma unroll
    for (int j = 0; j < 8; ++j) {
      float m = fmaxf(fmaxf(bf2f(n1[j]), bf2f(n2[j])), fmaxf(bf2f(n3[j]), bf2f(n4[j])));
      m = fmaxf(m - bf2f(c0[j]), 0.0f);
      res[j] = f2bf(m);
    }
    *(short8*)((short*)xjb + (rb + hw) * CC + co) = res;
  }
}

// ---------------- unified MFMA GEMM, BM=128, K in 192-chunks ----------------
// MODE 0: plain bf16 pm out; MODE 1: GELU bf16 pm out; MODE 2: swapped -> f32 channel-major
template<int NCHUNK, int MODE>
__global__ void __launch_bounds__(256) gemm_kernel(
    const __hip_bfloat16* __restrict__ actA, const __hip_bfloat16* __restrict__ actB,
    const __hip_bfloat16* __restrict__ Wf, const float* __restrict__ bfv,
    void* __restrict__ outp) {
  __shared__ char smem[128 * 384];
  const int t = threadIdx.x;
  const int lane = t & 63, w = t >> 6;
  const int wp = w & 1, wo = w >> 1;
  const int lrow = lane & 15, lhi = lane >> 4;
  const int P0 = blockIdx.x * 128;
  const int K_IN = NCHUNK * 192;
  f32x4 acc[4][6] = {};

  for (int ch = 0; ch < NCHUNK; ++ch) {
    if (ch) __syncthreads();
    const char* src = (const char*)((ch == 0) ? actA : actB) + (size_t)P0 * 384;
#pragma unroll
    for (int i = 0; i < 12; ++i) {
      int idx = i * 256 + t;
      int p = idx / 24, off = (idx - p * 24) * 16;
      short8 v = *(const short8*)(src + (size_t)p * 384 + off);
      *(short8*)(smem + p * 384 + (off ^ ((p & 7) << 4))) = v;
    }
    __syncthreads();
#pragma unroll
    for (int kk = 0; kk < 6; ++kk) {
      short8 af[4], wfr[6];
#pragma unroll
      for (int ai = 0; ai < 4; ++ai) {
        int p = wp * 64 + ai * 16 + lrow;
        int kbyte = kk * 64 + lhi * 16;
        af[ai] = *(const short8*)(smem + p * 384 + (kbyte ^ ((p & 7) << 4)));
      }
#pragma unroll
      for (int wi = 0; wi < 6; ++wi) {
        int o = wo * 96 + wi * 16 + lrow;
        wfr[wi] = *(const short8*)((const short*)Wf + (size_t)o * K_IN + ch * 192 + kk * 32 + lhi * 8);
      }
#pragma unroll
      for (int ai = 0; ai < 4; ++ai)
#pragma unroll
        for (int wi = 0; wi < 6; ++wi)
          acc[ai][wi] = (MODE == 2)
              ? __builtin_amdgcn_mfma_f32_16x16x32_bf16(wfr[wi], af[ai], acc[ai][wi], 0, 0, 0)
              : __builtin_amdgcn_mfma_f32_16x16x32_bf16(af[ai], wfr[wi], acc[ai][wi], 0, 0, 0);
    }
  }

  if (MODE != 2) {
#pragma unroll
    for (int wi = 0; wi < 6; ++wi) {
      int o = wo * 96 + wi * 16 + lrow;
      float bias = bfv[o];
#pragma unroll
      for (int ai = 0; ai < 4; ++ai) {
#pragma unroll
        for (int r = 0; r < 4; ++r) {
          int p = wp * 64 + ai * 16 + lhi * 4 + r;
          float v = acc[ai][wi][r] + bias;
          if (MODE == 1) v = geluf(v);
          *((short*)outp + (size_t)(P0 + p) * CC + o) = f2bf(v);
        }
      }
    }
  } else {
    const int b0 = P0 / HW, rem0 = P0 - b0 * HW;
#pragma unroll
    for (int wi = 0; wi < 6; ++wi) {
#pragma unroll
      for (int r = 0; r < 4; ++r) {
        int o = wo * 96 + wi * 16 + lhi * 4 + r;
        float bias = bfv[o];
#pragma unroll
        for (int ai = 0; ai < 4; ++ai) {
          int p = wp * 64 + ai * 16 + lrow;
          int hw = rem0 + p, bb = b0;
          if (hw >= HW) { bb++; hw -= HW; }
          ((float*)outp)[((size_t)bb * CC + o) * HW + hw] = acc[ai][wi][r] + bias;
        }
      }
    }
  }
}

extern "C" void kernel_launch(void* const* d_in, const int* in_sizes, int n_in,
                              void* d_out, int out_size, void* d_ws, size_t ws_size,
                              hipStream_t stream) {
  const float* x     = (const float*)d_in[0];
  const float* cpe_w = (const float*)d_in[1];
  const float* cpe_b = (const float*)d_in[2];
  const float* fc1_w = (const float*)d_in[3];
  const float* fc1_b = (const float*)d_in[4];
  const float* bn1_g = (const float*)d_in[5];
  const float* bn1_b = (const float*)d_in[6];
  const float* bn1_m = (const float*)d_in[7];
  const float* bn1_v = (const float*)d_in[8];
  const float* gc_w  = (const float*)d_in[9];
  const float* gc_b  = (const float*)d_in[10];
  const float* bng_g = (const float*)d_in[11];
  const float* bng_b = (const float*)d_in[12];
  const float* bng_m = (const float*)d_in[13];
  const float* bng_v = (const float*)d_in[14];
  const float* fc2_w = (const float*)d_in[15];
  const float* fc2_b = (const float*)d_in[16];
  const float* bn2_g = (const float*)d_in[17];
  const float* bn2_b = (const float*)d_in[18];
  const float* bn2_m = (const float*)d_in[19];
  const float* bn2_v = (const float*)d_in[20];

  if (ws_size < 77594624) return;
  char* ws = (char*)d_ws;
  __hip_bfloat16* W1f = (__hip_bfloat16*)(ws);
  __hip_bfloat16* Wgf = (__hip_bfloat16*)(ws + 73728);
  __hip_bfloat16* W2f = (__hip_bfloat16*)(ws + 221184);
  float* b1f = (float*)(ws + 294912);
  float* bgf = (float*)(ws + 295680);
  float* b2f = (float*)(ws + 296448);
  __hip_bfloat16* y0  = (__hip_bfloat16*)(ws + 524288);       // pixel-major; reused as y2
  __hip_bfloat16* xjb = (__hip_bfloat16*)(ws + 39059456);
  __hip_bfloat16* y1  = (__hip_bfloat16*)d_out;               // d_out as bf16 scratch
  float* out = (float*)d_out;

  fold_kernel<<<576, 256, 0, stream>>>(fc1_w, fc1_b, bn1_g, bn1_b, bn1_m, bn1_v,
      gc_w, gc_b, bng_g, bng_b, bng_m, bng_v, fc2_w, fc2_b, bn2_g, bn2_b, bn2_m, bn2_v,
      W1f, Wgf, W2f, b1f, bgf, b2f);
  dwconv_kernel<<<NB * 6 * 7, 256, 0, stream>>>(x, cpe_w, cpe_b, y0);
  gemm_kernel<1, 0><<<784, 256, 0, stream>>>(y0, nullptr, W1f, b1f, y1);
  xj_kernel<<<2048, 256, 0, stream>>>(y1, xjb);
  gemm_kernel<2, 1><<<784, 256, 0, stream>>>(y1, xjb, Wgf, bgf, y0);
  gemm_kernel<1, 2><<<784, 256, 0, stream>>>(y0, nullptr, W2f, b2f, out);
}

// Round 4
// 292.821 us; speedup vs baseline: 1.1712x; 1.1712x over previous
//
#include <hip/hip_runtime.h>
#include <hip/hip_bf16.h>

// Grapher block: RepCPE(dw7x7+res) -> fc1+BN -> MRConv4d(K=2) -> gc(2C->C)+BN+GELU -> fc2+BN
// B=32, C=192, H=W=56. d_in/d_out are FLOAT32; intermediates bf16.
//
//   fold:   BN-fold weights -> W1f[192][192], Wgf[192][384], W2f[192][192] (bf16), biases fp32
//   dwconv: (b, 32ch, 4rows) blocks, 41KB LDS (3 blocks/CU), residual in center tap,
//           out staged via LDS -> 64B-line stores, PIXEL-MAJOR bf16 y0
//   gemm1:  y1 = y0 * W1f^T        (BM=128, D[p][o])    -> y1 bf16 pm (d_out scratch)
//   xj:     max-relative 4 rolls   -> xjb bf16 pm
//   gemm2:  y2 = GELU([y1|xj]*Wgf) (2 K-chunks)         -> y2 bf16 pm
//   gemm3:  out = y2 * W2f^T       (swapped, D[o][p])   -> d_out f32 channel-major

#define CC   192
#define HW   3136
#define NB   32

using short8 = __attribute__((ext_vector_type(8))) short;
using f32x4  = __attribute__((ext_vector_type(4))) float;

__device__ __forceinline__ float bf2f(short s) {
  union { unsigned u; float f; } x; x.u = ((unsigned)(unsigned short)s) << 16; return x.f;
}
__device__ __forceinline__ short f2bf(float f) {
  __hip_bfloat16 h = __float2bfloat16(f);
  return *reinterpret_cast<short*>(&h);
}
__device__ __forceinline__ float geluf(float v) {
  return 0.5f * v * (1.0f + erff(v * 0.70710678118654752f));
}

// ---------------- fold: BN into weights/bias ----------------
__global__ void __launch_bounds__(256) fold_kernel(
    const float* __restrict__ fc1_w, const float* __restrict__ fc1_b,
    const float* __restrict__ bn1_g, const float* __restrict__ bn1_b,
    const float* __restrict__ bn1_m, const float* __restrict__ bn1_v,
    const float* __restrict__ gc_w,  const float* __restrict__ gc_b,
    const float* __restrict__ bng_g, const float* __restrict__ bng_b,
    const float* __restrict__ bng_m, const float* __restrict__ bng_v,
    const float* __restrict__ fc2_w, const float* __restrict__ fc2_b,
    const float* __restrict__ bn2_g, const float* __restrict__ bn2_b,
    const float* __restrict__ bn2_m, const float* __restrict__ bn2_v,
    __hip_bfloat16* __restrict__ W1f, __hip_bfloat16* __restrict__ Wgf, __hip_bfloat16* __restrict__ W2f,
    float* __restrict__ b1f, float* __restrict__ bgf, float* __restrict__ b2f) {
  int gt = blockIdx.x * 256 + threadIdx.x;
  if (gt < 3 * CC) {
    int which = gt / CC, o = gt - which * CC;
    const float *G, *Bt, *M, *V, *Bi; float* dst;
    if (which == 0)      { G = bn1_g; Bt = bn1_b; M = bn1_m; V = bn1_v; Bi = fc1_b; dst = b1f; }
    else if (which == 1) { G = bng_g; Bt = bng_b; M = bng_m; V = bng_v; Bi = gc_b;  dst = bgf; }
    else                 { G = bn2_g; Bt = bn2_b; M = bn2_m; V = bn2_v; Bi = fc2_b; dst = b2f; }
    float inv = G[o] * rsqrtf(V[o] + 1e-5f);
    dst[o] = Bi[o] * inv + Bt[o] - M[o] * inv;
  }
  int i = gt;
  if (i < CC * CC) {
    int o = i / CC;
    float inv = bn1_g[o] * rsqrtf(bn1_v[o] + 1e-5f);
    W1f[i] = __float2bfloat16(fc1_w[i] * inv);
  } else if (i < CC * CC + CC * 2 * CC) {
    int j = i - CC * CC; int o = j / (2 * CC);
    float inv = bng_g[o] * rsqrtf(bng_v[o] + 1e-5f);
    Wgf[j] = __float2bfloat16(gc_w[j] * inv);
  } else if (i < CC * CC * 4) {
    int j = i - CC * CC * 3; int o = j / CC;
    float inv = bn2_g[o] * rsqrtf(bn2_v[o] + 1e-5f);
    W2f[j] = __float2bfloat16(fc2_w[j] * inv);
  }
}

// ---------------- dw 7x7 + bias + residual -> PIXEL-MAJOR bf16 (v4) ----------------
// block: (b, cg of 32 ch, rs of 4 rows). LDS tile [32c][10r][64col] bf16, c-stride 644
// shorts (bank-step 2, conflict-free). col = w_global + 4 (halo 3, zero-padded).
// Thread (c = t&31, wg = t>>5 < 7): 8 cols x 4 rows per thread, weights+acc in regs.
// Output staged in LDS [224px][32c], stored as full 64B lines.
__global__ void __launch_bounds__(256) dwconv_kernel(
    const float* __restrict__ x, const float* __restrict__ cw,
    const float* __restrict__ cb, __hip_bfloat16* __restrict__ y0pm) {
  __shared__ short lds_s[32 * 644];            // 41216 B; reused as out_st[224][32]
  const int t = threadIdx.x;
  int bb = blockIdx.x;
  const int rs = bb % 14; bb /= 14;
  const int cg = bb % 6;  bb /= 6;
  const int b  = bb;
  const int h0 = rs * 4;

  // prezero (halo cols/rows must be 0)
  for (int i = t; i < 32 * 644 / 8; i += 256) ((int4*)lds_s)[i] = int4{0, 0, 0, 0};
  __syncthreads();

  // stage input rows h0-3 .. h0+6 (10 rows), 32 channels, bf16
  for (int it = t; it < 32 * 10 * 14; it += 256) {
    int w4 = it % 14, rr = (it / 14) % 10, c = it / 140;
    int gh = h0 - 3 + rr;
    if (gh >= 0 && gh < 56) {
      float4 v = *(const float4*)(x + ((size_t)(b * CC + cg * 32 + c) * 56 + gh) * 56 + w4 * 4);
      short4 s4 = { f2bf(v.x), f2bf(v.y), f2bf(v.z), f2bf(v.w) };
      *(short4*)(lds_s + c * 644 + rr * 64 + 4 + w4 * 4) = s4;
    }
  }

  const int c = t & 31, wg = t >> 5;
  float wreg[49];
  float bias = 0.0f;
  if (wg < 7) {
    const float* wp = cw + (cg * 32 + c) * 49;
#pragma unroll
    for (int i = 0; i < 49; ++i) wreg[i] = wp[i];
    wreg[24] += 1.0f;                          // residual = center tap + 1
    bias = cb[cg * 32 + c];
  }
  __syncthreads();

  float acc[4][8] = {};
  if (wg < 7) {
    const short* base = lds_s + c * 644 + wg * 8;
#pragma unroll
    for (int lr = 0; lr < 10; ++lr) {
      int2 q0 = *(const int2*)(base + lr * 64);
      int2 q1 = *(const int2*)(base + lr * 64 + 4);
      int2 q2 = *(const int2*)(base + lr * 64 + 8);
      int2 q3 = *(const int2*)(base + lr * 64 + 12);
      int dw[8] = { q0.x, q0.y, q1.x, q1.y, q2.x, q2.y, q3.x, q3.y };
      float v[16];
#pragma unroll
      for (int q = 0; q < 8; ++q) {
        union { int i; float f; } lo, hi;
        lo.i = dw[q] << 16; hi.i = dw[q] & 0xffff0000;
        v[q * 2] = lo.f; v[q * 2 + 1] = hi.f;
      }
#pragma unroll
      for (int r = 0; r < 4; ++r) {
        const int kh = lr - r;
        if (kh >= 0 && kh < 7) {
#pragma unroll
          for (int kw = 0; kw < 7; ++kw) {
            float wv = wreg[kh * 7 + kw];
#pragma unroll
            for (int ww = 0; ww < 8; ++ww)
              acc[r][ww] = fmaf(wv, v[1 + ww + kw], acc[r][ww]);
          }
        }
      }
    }
  }
  __syncthreads();                             // all reads of input tile done

  // stage output [224 px][32 c] bf16 over the same LDS
  if (wg < 7) {
#pragma unroll
    for (int r = 0; r < 4; ++r)
#pragma unroll
      for (int ww = 0; ww < 8; ++ww)
        lds_s[(r * 56 + wg * 8 + ww) * 32 + c] = f2bf(acc[r][ww] + bias);
  }
  __syncthreads();

  // cooperative store: full 64B lines, pixel-major
  short* dst = (short*)y0pm + ((size_t)b * HW + (size_t)h0 * 56) * CC + cg * 32;
  for (int it = t; it < 896; it += 256) {      // 224 px * 4 chunks of 8 ch
    int px = it >> 2, c8 = it & 3;
    short8 v = *(const short8*)(lds_s + px * 32 + c8 * 8);
    *(short8*)(dst + (size_t)px * CC + c8 * 8) = v;
  }
}

// ---------------- MRConv4d: x_j = relu(max(4 rolled) - center), pixel-major bf16 ----------------
__global__ void __launch_bounds__(256) xj_kernel(const __hip_bfloat16* __restrict__ y1,
                                                 __hip_bfloat16* __restrict__ xjb) {
  const int total = NB * HW * 24;
  const short* base = (const short*)y1;
  for (int idx = blockIdx.x * 256 + threadIdx.x; idx < total; idx += gridDim.x * 256) {
    int cg = idx % 24;
    int row = idx / 24;
    int b = row / HW, hw = row - b * HW;
    int h = hw / 56, wv = hw - h * 56;
    int hp = (h >= 54) ? h - 54 : h + 2;
    int hm = (h < 2) ? h + 54 : h - 2;
    int wpp = (wv >= 54) ? wv - 54 : wv + 2;
    int wmm = (wv < 2) ? wv + 54 : wv - 2;
    size_t rb = (size_t)b * HW;
    int co = cg * 8;
    short8 c0 = *(const short8*)(base + (rb + hw) * CC + co);
    short8 n1 = *(const short8*)(base + (rb + hp * 56 + wv) * CC + co);
    short8 n2 = *(const short8*)(base + (rb + hm * 56 + wv) * CC + co);
    short8 n3 = *(const short8*)(base + (rb + h * 56 + wpp) * CC + co);
    short8 n4 = *(const short8*)(base + (rb + h * 56 + wmm) * CC + co);
    short8 res;
#pragma unroll
    for (int j = 0; j < 8; ++j) {
      float m = fmaxf(fmaxf(bf2f(n1[j]), bf2f(n2[j])), fmaxf(bf2f(n3[j]), bf2f(n4[j])));
      m = fmaxf(m - bf2f(c0[j]), 0.0f);
      res[j] = f2bf(m);
    }
    *(short8*)((short*)xjb + (rb + hw) * CC + co) = res;
  }
}

// ---------------- unified MFMA GEMM, BM=128, K in 192-chunks ----------------
// MODE 0: plain bf16 pm out; MODE 1: GELU bf16 pm out; MODE 2: swapped -> f32 channel-major
template<int NCHUNK, int MODE>
__global__ void __launch_bounds__(256) gemm_kernel(
    const __hip_bfloat16* __restrict__ actA, const __hip_bfloat16* __restrict__ actB,
    const __hip_bfloat16* __restrict__ Wf, const float* __restrict__ bfv,
    void* __restrict__ outp) {
  __shared__ char smem[128 * 384];
  const int t = threadIdx.x;
  const int lane = t & 63, w = t >> 6;
  const int wp = w & 1, wo = w >> 1;
  const int lrow = lane & 15, lhi = lane >> 4;
  const int P0 = blockIdx.x * 128;
  const int K_IN = NCHUNK * 192;
  f32x4 acc[4][6] = {};

  for (int ch = 0; ch < NCHUNK; ++ch) {
    if (ch) __syncthreads();
    const char* src = (const char*)((ch == 0) ? actA : actB) + (size_t)P0 * 384;
#pragma unroll
    for (int i = 0; i < 12; ++i) {
      int idx = i * 256 + t;
      int p = idx / 24, off = (idx - p * 24) * 16;
      short8 v = *(const short8*)(src + (size_t)p * 384 + off);
      *(short8*)(smem + p * 384 + (off ^ ((p & 7) << 4))) = v;
    }
    __syncthreads();
#pragma unroll
    for (int kk = 0; kk < 6; ++kk) {
      short8 af[4], wfr[6];
#pragma unroll
      for (int ai = 0; ai < 4; ++ai) {
        int p = wp * 64 + ai * 16 + lrow;
        int kbyte = kk * 64 + lhi * 16;
        af[ai] = *(const short8*)(smem + p * 384 + (kbyte ^ ((p & 7) << 4)));
      }
#pragma unroll
      for (int wi = 0; wi < 6; ++wi) {
        int o = wo * 96 + wi * 16 + lrow;
        wfr[wi] = *(const short8*)((const short*)Wf + (size_t)o * K_IN + ch * 192 + kk * 32 + lhi * 8);
      }
#pragma unroll
      for (int ai = 0; ai < 4; ++ai)
#pragma unroll
        for (int wi = 0; wi < 6; ++wi)
          acc[ai][wi] = (MODE == 2)
              ? __builtin_amdgcn_mfma_f32_16x16x32_bf16(wfr[wi], af[ai], acc[ai][wi], 0, 0, 0)
              : __builtin_amdgcn_mfma_f32_16x16x32_bf16(af[ai], wfr[wi], acc[ai][wi], 0, 0, 0);
    }
  }

  if (MODE != 2) {
#pragma unroll
    for (int wi = 0; wi < 6; ++wi) {
      int o = wo * 96 + wi * 16 + lrow;
      float bias = bfv[o];
#pragma unroll
      for (int ai = 0; ai < 4; ++ai) {
#pragma unroll
        for (int r = 0; r < 4; ++r) {
          int p = wp * 64 + ai * 16 + lhi * 4 + r;
          float v = acc[ai][wi][r] + bias;
          if (MODE == 1) v = geluf(v);
          *((short*)outp + (size_t)(P0 + p) * CC + o) = f2bf(v);
        }
      }
    }
  } else {
    const int b0 = P0 / HW, rem0 = P0 - b0 * HW;
#pragma unroll
    for (int wi = 0; wi < 6; ++wi) {
#pragma unroll
      for (int r = 0; r < 4; ++r) {
        int o = wo * 96 + wi * 16 + lhi * 4 + r;
        float bias = bfv[o];
#pragma unroll
        for (int ai = 0; ai < 4; ++ai) {
          int p = wp * 64 + ai * 16 + lrow;
          int hw = rem0 + p, bb = b0;
          if (hw >= HW) { bb++; hw -= HW; }
          ((float*)outp)[((size_t)bb * CC + o) * HW + hw] = acc[ai][wi][r] + bias;
        }
      }
    }
  }
}

extern "C" void kernel_launch(void* const* d_in, const int* in_sizes, int n_in,
                              void* d_out, int out_size, void* d_ws, size_t ws_size,
                              hipStream_t stream) {
  const float* x     = (const float*)d_in[0];
  const float* cpe_w = (const float*)d_in[1];
  const float* cpe_b = (const float*)d_in[2];
  const float* fc1_w = (const float*)d_in[3];
  const float* fc1_b = (const float*)d_in[4];
  const float* bn1_g = (const float*)d_in[5];
  const float* bn1_b = (const float*)d_in[6];
  const float* bn1_m = (const float*)d_in[7];
  const float* bn1_v = (const float*)d_in[8];
  const float* gc_w  = (const float*)d_in[9];
  const float* gc_b  = (const float*)d_in[10];
  const float* bng_g = (const float*)d_in[11];
  const float* bng_b = (const float*)d_in[12];
  const float* bng_m = (const float*)d_in[13];
  const float* bng_v = (const float*)d_in[14];
  const float* fc2_w = (const float*)d_in[15];
  const float* fc2_b = (const float*)d_in[16];
  const float* bn2_g = (const float*)d_in[17];
  const float* bn2_b = (const float*)d_in[18];
  const float* bn2_m = (const float*)d_in[19];
  const float* bn2_v = (const float*)d_in[20];

  if (ws_size < 77594624) return;
  char* ws = (char*)d_ws;
  __hip_bfloat16* W1f = (__hip_bfloat16*)(ws);
  __hip_bfloat16* Wgf = (__hip_bfloat16*)(ws + 73728);
  __hip_bfloat16* W2f = (__hip_bfloat16*)(ws + 221184);
  float* b1f = (float*)(ws + 294912);
  float* bgf = (float*)(ws + 295680);
  float* b2f = (float*)(ws + 296448);
  __hip_bfloat16* y0  = (__hip_bfloat16*)(ws + 524288);       // pixel-major; reused as y2
  __hip_bfloat16* xjb = (__hip_bfloat16*)(ws + 39059456);
  __hip_bfloat16* y1  = (__hip_bfloat16*)d_out;               // d_out as bf16 scratch
  float* out = (float*)d_out;

  fold_kernel<<<576, 256, 0, stream>>>(fc1_w, fc1_b, bn1_g, bn1_b, bn1_m, bn1_v,
      gc_w, gc_b, bng_g, bng_b, bng_m, bng_v, fc2_w, fc2_b, bn2_g, bn2_b, bn2_m, bn2_v,
      W1f, Wgf, W2f, b1f, bgf, b2f);
  dwconv_kernel<<<NB * 6 * 14, 256, 0, stream>>>(x, cpe_w, cpe_b, y0);
  gemm_kernel<1, 0><<<784, 256, 0, stream>>>(y0, nullptr, W1f, b1f, y1);
  xj_kernel<<<2048, 256, 0, stream>>>(y1, xjb);
  gemm_kernel<2, 1><<<784, 256, 0, stream>>>(y1, xjb, Wgf, bgf, y0);
  gemm_kernel<1, 2><<<784, 256, 0, stream>>>(y0, nullptr, W2f, b2f, out);
}

// Round 5
// 226.950 us; speedup vs baseline: 1.5112x; 1.2902x over previous
//
#include <hip/hip_runtime.h>
#include <hip/hip_bf16.h>

// Grapher block: RepCPE(dw7x7+res) -> fc1+BN -> MRConv4d(K=2) -> gc(2C->C)+BN+GELU -> fc2+BN
// B=32, C=192, H=W=56. d_in/d_out FLOAT32; intermediates bf16.
//
//   fold:   BN-fold weights -> W1f[192][192], Wgf[192][384], W2f[192][192] (bf16), biases fp32
//   dwconv: (b, 32ch, 4rows) blocks, 41KB LDS, residual in center tap -> y0 pixel-major bf16
//   gemm*:  weight-stationary (48-o slice per wave in regs), grid-stride over 64-px tiles,
//           2-phase double-buffered LDS staging (stage next || compute cur), XOR-swizzled
//   gemm1:  y1 = y0*W1f^T  (D[p][o]) -> y1 bf16 pm (d_out scratch)
//   xj:     max-relative 4 rolls -> xjb bf16 pm
//   gemm2:  y2 = GELU([y1|xj]*Wgf) (2 chunks) -> y2 bf16 pm
//   gemm3:  out = y2*W2f^T (swapped ops, D[o][p]) -> d_out f32 channel-major

#define CC   192
#define HW   3136
#define NB   32

using short8 = __attribute__((ext_vector_type(8))) short;
using f32x4  = __attribute__((ext_vector_type(4))) float;

__device__ __forceinline__ float bf2f(short s) {
  union { unsigned u; float f; } x; x.u = ((unsigned)(unsigned short)s) << 16; return x.f;
}
__device__ __forceinline__ short f2bf(float f) {
  __hip_bfloat16 h = __float2bfloat16(f);
  return *reinterpret_cast<short*>(&h);
}
__device__ __forceinline__ float geluf(float v) {
  return 0.5f * v * (1.0f + erff(v * 0.70710678118654752f));
}

// ---------------- fold: BN into weights/bias ----------------
__global__ void __launch_bounds__(256) fold_kernel(
    const float* __restrict__ fc1_w, const float* __restrict__ fc1_b,
    const float* __restrict__ bn1_g, const float* __restrict__ bn1_b,
    const float* __restrict__ bn1_m, const float* __restrict__ bn1_v,
    const float* __restrict__ gc_w,  const float* __restrict__ gc_b,
    const float* __restrict__ bng_g, const float* __restrict__ bng_b,
    const float* __restrict__ bng_m, const float* __restrict__ bng_v,
    const float* __restrict__ fc2_w, const float* __restrict__ fc2_b,
    const float* __restrict__ bn2_g, const float* __restrict__ bn2_b,
    const float* __restrict__ bn2_m, const float* __restrict__ bn2_v,
    __hip_bfloat16* __restrict__ W1f, __hip_bfloat16* __restrict__ Wgf, __hip_bfloat16* __restrict__ W2f,
    float* __restrict__ b1f, float* __restrict__ bgf, float* __restrict__ b2f) {
  int gt = blockIdx.x * 256 + threadIdx.x;
  if (gt < 3 * CC) {
    int which = gt / CC, o = gt - which * CC;
    const float *G, *Bt, *M, *V, *Bi; float* dst;
    if (which == 0)      { G = bn1_g; Bt = bn1_b; M = bn1_m; V = bn1_v; Bi = fc1_b; dst = b1f; }
    else if (which == 1) { G = bng_g; Bt = bng_b; M = bng_m; V = bng_v; Bi = gc_b;  dst = bgf; }
    else                 { G = bn2_g; Bt = bn2_b; M = bn2_m; V = bn2_v; Bi = fc2_b; dst = b2f; }
    float inv = G[o] * rsqrtf(V[o] + 1e-5f);
    dst[o] = Bi[o] * inv + Bt[o] - M[o] * inv;
  }
  int i = gt;
  if (i < CC * CC) {
    int o = i / CC;
    float inv = bn1_g[o] * rsqrtf(bn1_v[o] + 1e-5f);
    W1f[i] = __float2bfloat16(fc1_w[i] * inv);
  } else if (i < CC * CC + CC * 2 * CC) {
    int j = i - CC * CC; int o = j / (2 * CC);
    float inv = bng_g[o] * rsqrtf(bng_v[o] + 1e-5f);
    Wgf[j] = __float2bfloat16(gc_w[j] * inv);
  } else if (i < CC * CC * 4) {
    int j = i - CC * CC * 3; int o = j / CC;
    float inv = bn2_g[o] * rsqrtf(bn2_v[o] + 1e-5f);
    W2f[j] = __float2bfloat16(fc2_w[j] * inv);
  }
}

// ---------------- dw 7x7 + bias + residual -> PIXEL-MAJOR bf16 (unchanged from R3) ----------------
__global__ void __launch_bounds__(256) dwconv_kernel(
    const float* __restrict__ x, const float* __restrict__ cw,
    const float* __restrict__ cb, __hip_bfloat16* __restrict__ y0pm) {
  __shared__ short lds_s[32 * 644];            // 41216 B; reused as out_st[224][32]
  const int t = threadIdx.x;
  int bb = blockIdx.x;
  const int rs = bb % 14; bb /= 14;
  const int cg = bb % 6;  bb /= 6;
  const int b  = bb;
  const int h0 = rs * 4;

  for (int i = t; i < 32 * 644 / 8; i += 256) ((int4*)lds_s)[i] = int4{0, 0, 0, 0};
  __syncthreads();

  for (int it = t; it < 32 * 10 * 14; it += 256) {
    int w4 = it % 14, rr = (it / 14) % 10, c = it / 140;
    int gh = h0 - 3 + rr;
    if (gh >= 0 && gh < 56) {
      float4 v = *(const float4*)(x + ((size_t)(b * CC + cg * 32 + c) * 56 + gh) * 56 + w4 * 4);
      short4 s4 = { f2bf(v.x), f2bf(v.y), f2bf(v.z), f2bf(v.w) };
      *(short4*)(lds_s + c * 644 + rr * 64 + 4 + w4 * 4) = s4;
    }
  }

  const int c = t & 31, wg = t >> 5;
  float wreg[49];
  float bias = 0.0f;
  if (wg < 7) {
    const float* wp = cw + (cg * 32 + c) * 49;
#pragma unroll
    for (int i = 0; i < 49; ++i) wreg[i] = wp[i];
    wreg[24] += 1.0f;                          // residual = center tap + 1
    bias = cb[cg * 32 + c];
  }
  __syncthreads();

  float acc[4][8] = {};
  if (wg < 7) {
    const short* base = lds_s + c * 644 + wg * 8;
#pragma unroll
    for (int lr = 0; lr < 10; ++lr) {
      int2 q0 = *(const int2*)(base + lr * 64);
      int2 q1 = *(const int2*)(base + lr * 64 + 4);
      int2 q2 = *(const int2*)(base + lr * 64 + 8);
      int2 q3 = *(const int2*)(base + lr * 64 + 12);
      int dw[8] = { q0.x, q0.y, q1.x, q1.y, q2.x, q2.y, q3.x, q3.y };
      float v[16];
#pragma unroll
      for (int q = 0; q < 8; ++q) {
        union { int i; float f; } lo, hi;
        lo.i = dw[q] << 16; hi.i = dw[q] & 0xffff0000;
        v[q * 2] = lo.f; v[q * 2 + 1] = hi.f;
      }
#pragma unroll
      for (int r = 0; r < 4; ++r) {
        const int kh = lr - r;
        if (kh >= 0 && kh < 7) {
#pragma unroll
          for (int kw = 0; kw < 7; ++kw) {
            float wv = wreg[kh * 7 + kw];
#pragma unroll
            for (int ww = 0; ww < 8; ++ww)
              acc[r][ww] = fmaf(wv, v[1 + ww + kw], acc[r][ww]);
          }
        }
      }
    }
  }
  __syncthreads();

  if (wg < 7) {
#pragma unroll
    for (int r = 0; r < 4; ++r)
#pragma unroll
      for (int ww = 0; ww < 8; ++ww)
        lds_s[(r * 56 + wg * 8 + ww) * 32 + c] = f2bf(acc[r][ww] + bias);
  }
  __syncthreads();

  short* dst = (short*)y0pm + ((size_t)b * HW + (size_t)h0 * 56) * CC + cg * 32;
  for (int it = t; it < 896; it += 256) {
    int px = it >> 2, c8 = it & 3;
    short8 v = *(const short8*)(lds_s + px * 32 + c8 * 8);
    *(short8*)(dst + (size_t)px * CC + c8 * 8) = v;
  }
}

// ---------------- MRConv4d: x_j = relu(max(4 rolled) - center), pixel-major bf16 ----------------
__global__ void __launch_bounds__(256) xj_kernel(const __hip_bfloat16* __restrict__ y1,
                                                 __hip_bfloat16* __restrict__ xjb) {
  const int total = NB * HW * 24;
  const short* base = (const short*)y1;
  for (int idx = blockIdx.x * 256 + threadIdx.x; idx < total; idx += gridDim.x * 256) {
    int cg = idx % 24;
    int row = idx / 24;
    int b = row / HW, hw = row - b * HW;
    int h = hw / 56, wv = hw - h * 56;
    int hp = (h >= 54) ? h - 54 : h + 2;
    int hm = (h < 2) ? h + 54 : h - 2;
    int wpp = (wv >= 54) ? wv - 54 : wv + 2;
    int wmm = (wv < 2) ? wv + 54 : wv - 2;
    size_t rb = (size_t)b * HW;
    int co = cg * 8;
    short8 c0 = *(const short8*)(base + (rb + hw) * CC + co);
    short8 n1 = *(const short8*)(base + (rb + hp * 56 + wv) * CC + co);
    short8 n2 = *(const short8*)(base + (rb + hm * 56 + wv) * CC + co);
    short8 n3 = *(const short8*)(base + (rb + h * 56 + wpp) * CC + co);
    short8 n4 = *(const short8*)(base + (rb + h * 56 + wmm) * CC + co);
    short8 res;
#pragma unroll
    for (int j = 0; j < 8; ++j) {
      float m = fmaxf(fmaxf(bf2f(n1[j]), bf2f(n2[j])), fmaxf(bf2f(n3[j]), bf2f(n4[j])));
      m = fmaxf(m - bf2f(c0[j]), 0.0f);
      res[j] = f2bf(m);
    }
    *(short8*)((short*)xjb + (rb + hw) * CC + co) = res;
  }
}

// ---------------- gemm v3: weight-stationary, grid-stride, 2-phase dbuf ----------------
__device__ __forceinline__ void stage_tile(char* dst, const char* src,
                                           const int* sp, const int* sq) {
#pragma unroll
  for (int j = 0; j < 6; ++j) {
    short8 v = *(const short8*)(src + (size_t)sp[j] * 384 + sq[j]);
    *(short8*)(dst + sp[j] * 384 + (sq[j] ^ ((sp[j] & 7) << 4))) = v;
  }
}

template<int K_IN>
__device__ __forceinline__ void wload(short8 (&wreg)[6][3], const short* Wf,
                                      int w, int lrow, int lhi, int koff) {
#pragma unroll
  for (int kk = 0; kk < 6; ++kk)
#pragma unroll
    for (int wi = 0; wi < 3; ++wi) {
      int o = w * 48 + wi * 16 + lrow;
      wreg[kk][wi] = *(const short8*)(Wf + (size_t)o * K_IN + koff + kk * 32 + lhi * 8);
    }
}

// MODE 0: bf16 pm out; MODE 1: GELU bf16 pm out; MODE 2: swapped -> f32 channel-major
template<int NCHUNK, int MODE>
__global__ void __launch_bounds__(256, 2) gemm_kernel(
    const __hip_bfloat16* __restrict__ actA, const __hip_bfloat16* __restrict__ actB,
    const __hip_bfloat16* __restrict__ Wf, const float* __restrict__ bfv,
    void* __restrict__ outp) {
  __shared__ char smem[2][24576];
  const int t = threadIdx.x;
  const int lane = t & 63, w = t >> 6;
  const int lrow = lane & 15, lhi = lane >> 4;
  constexpr int K_IN = NCHUNK * 192;
  constexpr int NT = NB * 49;          // 1568 pixel tiles of 64

  int sp[6], sq[6];
#pragma unroll
  for (int j = 0; j < 6; ++j) {
    int idx = j * 256 + t;
    sp[j] = idx / 24;
    sq[j] = (idx - sp[j] * 24) * 16;
  }

  float bw0[3];
  float bw2[3][4];
  if (MODE != 2) {
#pragma unroll
    for (int wi = 0; wi < 3; ++wi) bw0[wi] = bfv[w * 48 + wi * 16 + lrow];
  } else {
#pragma unroll
    for (int wi = 0; wi < 3; ++wi)
#pragma unroll
      for (int r = 0; r < 4; ++r) bw2[wi][r] = bfv[w * 48 + wi * 16 + lhi * 4 + r];
  }

  short8 wreg[6][3];
  if (NCHUNK == 1) wload<K_IN>(wreg, (const short*)Wf, w, lrow, lhi, 0);

  const int step = gridDim.x;
  int tile = blockIdx.x;
  stage_tile(smem[0], (const char*)actA + (size_t)tile * 24576, sp, sq);
  __syncthreads();
  int cur = 0;

  while (tile < NT) {
    const int tnext = tile + step;
    f32x4 acc[4][3] = {};
#pragma unroll
    for (int c = 0; c < NCHUNK; ++c) {
      // issue next stage into the other buffer (overlaps with compute below)
      if (c + 1 < NCHUNK)
        stage_tile(smem[cur ^ 1], (const char*)actB + (size_t)tile * 24576, sp, sq);
      else if (tnext < NT)
        stage_tile(smem[cur ^ 1], (const char*)actA + (size_t)tnext * 24576, sp, sq);
      if (NCHUNK > 1) wload<K_IN>(wreg, (const short*)Wf, w, lrow, lhi, c * 192);
#pragma unroll
      for (int kk = 0; kk < 6; ++kk) {
        short8 af[4];
#pragma unroll
        for (int ai = 0; ai < 4; ++ai) {
          int p = ai * 16 + lrow;
          af[ai] = *(const short8*)(smem[cur] + p * 384 + ((kk * 64 + lhi * 16) ^ ((p & 7) << 4)));
        }
#pragma unroll
        for (int ai = 0; ai < 4; ++ai)
#pragma unroll
          for (int wi = 0; wi < 3; ++wi)
            acc[ai][wi] = (MODE == 2)
                ? __builtin_amdgcn_mfma_f32_16x16x32_bf16(wreg[kk][wi], af[ai], acc[ai][wi], 0, 0, 0)
                : __builtin_amdgcn_mfma_f32_16x16x32_bf16(af[ai], wreg[kk][wi], acc[ai][wi], 0, 0, 0);
      }
      __syncthreads();
      cur ^= 1;
    }
    // epilogue
    if (MODE != 2) {
      short* ob = (short*)outp + (size_t)tile * 64 * CC;
#pragma unroll
      for (int wi = 0; wi < 3; ++wi) {
        int o = w * 48 + wi * 16 + lrow;
#pragma unroll
        for (int ai = 0; ai < 4; ++ai)
#pragma unroll
          for (int r = 0; r < 4; ++r) {
            int p = ai * 16 + lhi * 4 + r;
            float v = acc[ai][wi][r] + bw0[wi];
            if (MODE == 1) v = geluf(v);
            ob[(size_t)p * CC + o] = f2bf(v);
          }
      }
    } else {
      int b = tile / 49, hw0 = (tile - b * 49) * 64;
      float* ob = (float*)outp + (size_t)b * CC * HW + hw0;
#pragma unroll
      for (int wi = 0; wi < 3; ++wi)
#pragma unroll
        for (int r = 0; r < 4; ++r) {
          int o = w * 48 + wi * 16 + lhi * 4 + r;
#pragma unroll
          for (int ai = 0; ai < 4; ++ai)
            ob[(size_t)o * HW + ai * 16 + lrow] = acc[ai][wi][r] + bw2[wi][r];
        }
    }
    tile = tnext;
  }
}

extern "C" void kernel_launch(void* const* d_in, const int* in_sizes, int n_in,
                              void* d_out, int out_size, void* d_ws, size_t ws_size,
                              hipStream_t stream) {
  const float* x     = (const float*)d_in[0];
  const float* cpe_w = (const float*)d_in[1];
  const float* cpe_b = (const float*)d_in[2];
  const float* fc1_w = (const float*)d_in[3];
  const float* fc1_b = (const float*)d_in[4];
  const float* bn1_g = (const float*)d_in[5];
  const float* bn1_b = (const float*)d_in[6];
  const float* bn1_m = (const float*)d_in[7];
  const float* bn1_v = (const float*)d_in[8];
  const float* gc_w  = (const float*)d_in[9];
  const float* gc_b  = (const float*)d_in[10];
  const float* bng_g = (const float*)d_in[11];
  const float* bng_b = (const float*)d_in[12];
  const float* bng_m = (const float*)d_in[13];
  const float* bng_v = (const float*)d_in[14];
  const float* fc2_w = (const float*)d_in[15];
  const float* fc2_b = (const float*)d_in[16];
  const float* bn2_g = (const float*)d_in[17];
  const float* bn2_b = (const float*)d_in[18];
  const float* bn2_m = (const float*)d_in[19];
  const float* bn2_v = (const float*)d_in[20];

  if (ws_size < 77594624) return;
  char* ws = (char*)d_ws;
  __hip_bfloat16* W1f = (__hip_bfloat16*)(ws);
  __hip_bfloat16* Wgf = (__hip_bfloat16*)(ws + 73728);
  __hip_bfloat16* W2f = (__hip_bfloat16*)(ws + 221184);
  float* b1f = (float*)(ws + 294912);
  float* bgf = (float*)(ws + 295680);
  float* b2f = (float*)(ws + 296448);
  __hip_bfloat16* y0  = (__hip_bfloat16*)(ws + 524288);       // pixel-major; reused as y2
  __hip_bfloat16* xjb = (__hip_bfloat16*)(ws + 39059456);
  __hip_bfloat16* y1  = (__hip_bfloat16*)d_out;               // d_out as bf16 scratch
  float* out = (float*)d_out;

  fold_kernel<<<576, 256, 0, stream>>>(fc1_w, fc1_b, bn1_g, bn1_b, bn1_m, bn1_v,
      gc_w, gc_b, bng_g, bng_b, bng_m, bng_v, fc2_w, fc2_b, bn2_g, bn2_b, bn2_m, bn2_v,
      W1f, Wgf, W2f, b1f, bgf, b2f);
  dwconv_kernel<<<NB * 6 * 14, 256, 0, stream>>>(x, cpe_w, cpe_b, y0);
  gemm_kernel<1, 0><<<512, 256, 0, stream>>>(y0, nullptr, W1f, b1f, y1);
  xj_kernel<<<2048, 256, 0, stream>>>(y1, xjb);
  gemm_kernel<2, 1><<<512, 256, 0, stream>>>(y1, xjb, Wgf, bgf, y0);
  gemm_kernel<1, 2><<<512, 256, 0, stream>>>(y0, nullptr, W2f, b2f, out);
}

// Round 6
// 207.016 us; speedup vs baseline: 1.6567x; 1.0963x over previous
//
#include <hip/hip_runtime.h>
#include <hip/hip_bf16.h>

// Grapher block: RepCPE(dw7x7+res) -> fc1+BN -> MRConv4d(K=2) -> gc(2C->C)+BN+GELU -> fc2+BN
// B=32, C=192, H=W=56. d_in/d_out FLOAT32; intermediates bf16.
//
//   fold:   BN-fold weights -> W1f[192][192], Wgf[192][384], W2f[192][192] (bf16), biases fp32
//   dwconv: v5 - (b,16ch,8rows) blocks, 30.6KB LDS (4 blocks/CU), bf16 tile stride-956,
//           residual in center tap, direct 32B-chunk global stores -> y0 pixel-major bf16
//   gemm*:  weight-stationary (48-o slice per wave in regs), grid-stride over 64-px tiles,
//           2-phase double-buffered LDS staging, XOR-swizzled
//   gemm1:  y1 = y0*W1f^T  (D[p][o]) -> y1 bf16 pm (d_out scratch)
//   xj:     max-relative 4 rolls -> xjb bf16 pm
//   gemm2:  y2 = GELU([y1|xj]*Wgf) (2 chunks) -> y2 bf16 pm
//   gemm3:  out = y2*W2f^T (swapped ops, D[o][p]) -> d_out f32 channel-major

#define CC   192
#define HW   3136
#define NB   32

using short8 = __attribute__((ext_vector_type(8))) short;
using f32x4  = __attribute__((ext_vector_type(4))) float;

__device__ __forceinline__ float bf2f(short s) {
  union { unsigned u; float f; } x; x.u = ((unsigned)(unsigned short)s) << 16; return x.f;
}
__device__ __forceinline__ short f2bf(float f) {
  __hip_bfloat16 h = __float2bfloat16(f);
  return *reinterpret_cast<short*>(&h);
}
__device__ __forceinline__ float geluf(float v) {
  return 0.5f * v * (1.0f + erff(v * 0.70710678118654752f));
}

// ---------------- fold: BN into weights/bias ----------------
__global__ void __launch_bounds__(256) fold_kernel(
    const float* __restrict__ fc1_w, const float* __restrict__ fc1_b,
    const float* __restrict__ bn1_g, const float* __restrict__ bn1_b,
    const float* __restrict__ bn1_m, const float* __restrict__ bn1_v,
    const float* __restrict__ gc_w,  const float* __restrict__ gc_b,
    const float* __restrict__ bng_g, const float* __restrict__ bng_b,
    const float* __restrict__ bng_m, const float* __restrict__ bng_v,
    const float* __restrict__ fc2_w, const float* __restrict__ fc2_b,
    const float* __restrict__ bn2_g, const float* __restrict__ bn2_b,
    const float* __restrict__ bn2_m, const float* __restrict__ bn2_v,
    __hip_bfloat16* __restrict__ W1f, __hip_bfloat16* __restrict__ Wgf, __hip_bfloat16* __restrict__ W2f,
    float* __restrict__ b1f, float* __restrict__ bgf, float* __restrict__ b2f) {
  int gt = blockIdx.x * 256 + threadIdx.x;
  if (gt < 3 * CC) {
    int which = gt / CC, o = gt - which * CC;
    const float *G, *Bt, *M, *V, *Bi; float* dst;
    if (which == 0)      { G = bn1_g; Bt = bn1_b; M = bn1_m; V = bn1_v; Bi = fc1_b; dst = b1f; }
    else if (which == 1) { G = bng_g; Bt = bng_b; M = bng_m; V = bng_v; Bi = gc_b;  dst = bgf; }
    else                 { G = bn2_g; Bt = bn2_b; M = bn2_m; V = bn2_v; Bi = fc2_b; dst = b2f; }
    float inv = G[o] * rsqrtf(V[o] + 1e-5f);
    dst[o] = Bi[o] * inv + Bt[o] - M[o] * inv;
  }
  int i = gt;
  if (i < CC * CC) {
    int o = i / CC;
    float inv = bn1_g[o] * rsqrtf(bn1_v[o] + 1e-5f);
    W1f[i] = __float2bfloat16(fc1_w[i] * inv);
  } else if (i < CC * CC + CC * 2 * CC) {
    int j = i - CC * CC; int o = j / (2 * CC);
    float inv = bng_g[o] * rsqrtf(bng_v[o] + 1e-5f);
    Wgf[j] = __float2bfloat16(gc_w[j] * inv);
  } else if (i < CC * CC * 4) {
    int j = i - CC * CC * 3; int o = j / CC;
    float inv = bn2_g[o] * rsqrtf(bn2_v[o] + 1e-5f);
    W2f[j] = __float2bfloat16(fc2_w[j] * inv);
  }
}

// ---------------- dw 7x7 + bias + residual -> PIXEL-MAJOR bf16 (v5) ----------------
// block: (b, cg of 16 ch, rs of 8 rows). LDS in_t[16 c][14 r][68 col] bf16, c-stride 956
// shorts (16 distinct bank starts). col = w + 4 (halo 3 + 1 align, zero-padded).
// thread: c = t&15, g = t>>4 (<14): cgx = g%7 owns 8 cols, rh = g/7 owns 4 rows.
// Direct global stores: 16 c-lanes form one aligned 32B chunk per store instr.
#define CSTR 956
__global__ void __launch_bounds__(256, 4) dwconv_kernel(
    const float* __restrict__ x, const float* __restrict__ cw,
    const float* __restrict__ cb, __hip_bfloat16* __restrict__ y0pm) {
  __shared__ short in_t[16 * CSTR];            // 30592 B
  const int t = threadIdx.x;
  int bb = blockIdx.x;
  const int rs = bb % 7;  bb /= 7;
  const int cg = bb % 12; bb /= 12;
  const int b  = bb;
  const int h0 = rs * 8;

  for (int i = t; i < 16 * CSTR / 8; i += 256) ((int4*)in_t)[i] = int4{0, 0, 0, 0};
  __syncthreads();

  // stage rows h0-3 .. h0+10 (14 rows), 16 channels, bf16
  for (int it = t; it < 16 * 14 * 14; it += 256) {
    int w4 = it % 14, rr = (it / 14) % 14, c = it / 196;
    int gh = h0 - 3 + rr;
    if (gh >= 0 && gh < 56) {
      float4 v = *(const float4*)(x + ((size_t)(b * CC + cg * 16 + c) * 56 + gh) * 56 + w4 * 4);
      short4 s4 = { f2bf(v.x), f2bf(v.y), f2bf(v.z), f2bf(v.w) };
      *(short4*)(in_t + c * CSTR + rr * 68 + 4 + w4 * 4) = s4;
    }
  }

  const int c = t & 15, g = t >> 4;
  const int cgx = g % 7, rh = g / 7;           // g<14 active
  float wreg[49];
  float bias = 0.0f;
  if (g < 14) {
    const float* wp = cw + (cg * 16 + c) * 49;
#pragma unroll
    for (int i = 0; i < 49; ++i) wreg[i] = wp[i];
    wreg[24] += 1.0f;                          // residual = center tap + 1
    bias = cb[cg * 16 + c];
  }
  __syncthreads();

  if (g < 14) {
    float acc[4][8] = {};
    const short* base = in_t + c * CSTR + rh * 4 * 68 + cgx * 8;
#pragma unroll
    for (int lr = 0; lr < 10; ++lr) {
      int2 q0 = *(const int2*)(base + lr * 68);
      int2 q1 = *(const int2*)(base + lr * 68 + 4);
      int2 q2 = *(const int2*)(base + lr * 68 + 8);
      int2 q3 = *(const int2*)(base + lr * 68 + 12);
      int dw[8] = { q0.x, q0.y, q1.x, q1.y, q2.x, q2.y, q3.x, q3.y };
      float v[16];
#pragma unroll
      for (int q = 0; q < 8; ++q) {
        union { int i; float f; } lo, hi;
        lo.i = dw[q] << 16; hi.i = dw[q] & 0xffff0000;
        v[q * 2] = lo.f; v[q * 2 + 1] = hi.f;
      }
#pragma unroll
      for (int r = 0; r < 4; ++r) {
        const int kh = lr - r;
        if (kh >= 0 && kh < 7) {
#pragma unroll
          for (int kw = 0; kw < 7; ++kw) {
            float wv = wreg[kh * 7 + kw];
#pragma unroll
            for (int ww = 0; ww < 8; ++ww)
              acc[r][ww] = fmaf(wv, v[ww + kw + 1], acc[r][ww]);
          }
        }
      }
    }
    // direct pixel-major stores: 16 c-lanes = one aligned 32B chunk
    short* dst = (short*)y0pm + ((size_t)b * HW + (size_t)(h0 + rh * 4) * 56 + cgx * 8) * CC
                 + cg * 16 + c;
#pragma unroll
    for (int r = 0; r < 4; ++r)
#pragma unroll
      for (int ww = 0; ww < 8; ++ww)
        dst[(size_t)(r * 56 + ww) * CC] = f2bf(acc[r][ww] + bias);
  }
}

// ---------------- MRConv4d: x_j = relu(max(4 rolled) - center), pixel-major bf16 ----------------
__global__ void __launch_bounds__(256) xj_kernel(const __hip_bfloat16* __restrict__ y1,
                                                 __hip_bfloat16* __restrict__ xjb) {
  const int total = NB * HW * 24;
  const short* base = (const short*)y1;
  for (int idx = blockIdx.x * 256 + threadIdx.x; idx < total; idx += gridDim.x * 256) {
    int cg = idx % 24;
    int row = idx / 24;
    int b = row / HW, hw = row - b * HW;
    int h = hw / 56, wv = hw - h * 56;
    int hp = (h >= 54) ? h - 54 : h + 2;
    int hm = (h < 2) ? h + 54 : h - 2;
    int wpp = (wv >= 54) ? wv - 54 : wv + 2;
    int wmm = (wv < 2) ? wv + 54 : wv - 2;
    size_t rb = (size_t)b * HW;
    int co = cg * 8;
    short8 c0 = *(const short8*)(base + (rb + hw) * CC + co);
    short8 n1 = *(const short8*)(base + (rb + hp * 56 + wv) * CC + co);
    short8 n2 = *(const short8*)(base + (rb + hm * 56 + wv) * CC + co);
    short8 n3 = *(const short8*)(base + (rb + h * 56 + wpp) * CC + co);
    short8 n4 = *(const short8*)(base + (rb + h * 56 + wmm) * CC + co);
    short8 res;
#pragma unroll
    for (int j = 0; j < 8; ++j) {
      float m = fmaxf(fmaxf(bf2f(n1[j]), bf2f(n2[j])), fmaxf(bf2f(n3[j]), bf2f(n4[j])));
      m = fmaxf(m - bf2f(c0[j]), 0.0f);
      res[j] = f2bf(m);
    }
    *(short8*)((short*)xjb + (rb + hw) * CC + co) = res;
  }
}

// ---------------- gemm v3: weight-stationary, grid-stride, 2-phase dbuf ----------------
__device__ __forceinline__ void stage_tile(char* dst, const char* src,
                                           const int* sp, const int* sq) {
#pragma unroll
  for (int j = 0; j < 6; ++j) {
    short8 v = *(const short8*)(src + (size_t)sp[j] * 384 + sq[j]);
    *(short8*)(dst + sp[j] * 384 + (sq[j] ^ ((sp[j] & 7) << 4))) = v;
  }
}

template<int K_IN>
__device__ __forceinline__ void wload(short8 (&wreg)[6][3], const short* Wf,
                                      int w, int lrow, int lhi, int koff) {
#pragma unroll
  for (int kk = 0; kk < 6; ++kk)
#pragma unroll
    for (int wi = 0; wi < 3; ++wi) {
      int o = w * 48 + wi * 16 + lrow;
      wreg[kk][wi] = *(const short8*)(Wf + (size_t)o * K_IN + koff + kk * 32 + lhi * 8);
    }
}

// MODE 0: bf16 pm out; MODE 1: GELU bf16 pm out; MODE 2: swapped -> f32 channel-major
template<int NCHUNK, int MODE>
__global__ void __launch_bounds__(256, 2) gemm_kernel(
    const __hip_bfloat16* __restrict__ actA, const __hip_bfloat16* __restrict__ actB,
    const __hip_bfloat16* __restrict__ Wf, const float* __restrict__ bfv,
    void* __restrict__ outp) {
  __shared__ char smem[2][24576];
  const int t = threadIdx.x;
  const int lane = t & 63, w = t >> 6;
  const int lrow = lane & 15, lhi = lane >> 4;
  constexpr int K_IN = NCHUNK * 192;
  constexpr int NT = NB * 49;          // 1568 pixel tiles of 64

  int sp[6], sq[6];
#pragma unroll
  for (int j = 0; j < 6; ++j) {
    int idx = j * 256 + t;
    sp[j] = idx / 24;
    sq[j] = (idx - sp[j] * 24) * 16;
  }

  float bw0[3];
  float bw2[3][4];
  if (MODE != 2) {
#pragma unroll
    for (int wi = 0; wi < 3; ++wi) bw0[wi] = bfv[w * 48 + wi * 16 + lrow];
  } else {
#pragma unroll
    for (int wi = 0; wi < 3; ++wi)
#pragma unroll
      for (int r = 0; r < 4; ++r) bw2[wi][r] = bfv[w * 48 + wi * 16 + lhi * 4 + r];
  }

  short8 wreg[6][3];
  if (NCHUNK == 1) wload<K_IN>(wreg, (const short*)Wf, w, lrow, lhi, 0);

  const int step = gridDim.x;
  int tile = blockIdx.x;
  stage_tile(smem[0], (const char*)actA + (size_t)tile * 24576, sp, sq);
  __syncthreads();
  int cur = 0;

  while (tile < NT) {
    const int tnext = tile + step;
    f32x4 acc[4][3] = {};
#pragma unroll
    for (int c = 0; c < NCHUNK; ++c) {
      // issue next stage into the other buffer (overlaps with compute below)
      if (c + 1 < NCHUNK)
        stage_tile(smem[cur ^ 1], (const char*)actB + (size_t)tile * 24576, sp, sq);
      else if (tnext < NT)
        stage_tile(smem[cur ^ 1], (const char*)actA + (size_t)tnext * 24576, sp, sq);
      if (NCHUNK > 1) wload<K_IN>(wreg, (const short*)Wf, w, lrow, lhi, c * 192);
#pragma unroll
      for (int kk = 0; kk < 6; ++kk) {
        short8 af[4];
#pragma unroll
        for (int ai = 0; ai < 4; ++ai) {
          int p = ai * 16 + lrow;
          af[ai] = *(const short8*)(smem[cur] + p * 384 + ((kk * 64 + lhi * 16) ^ ((p & 7) << 4)));
        }
#pragma unroll
        for (int ai = 0; ai < 4; ++ai)
#pragma unroll
          for (int wi = 0; wi < 3; ++wi)
            acc[ai][wi] = (MODE == 2)
                ? __builtin_amdgcn_mfma_f32_16x16x32_bf16(wreg[kk][wi], af[ai], acc[ai][wi], 0, 0, 0)
                : __builtin_amdgcn_mfma_f32_16x16x32_bf16(af[ai], wreg[kk][wi], acc[ai][wi], 0, 0, 0);
      }
      __syncthreads();
      cur ^= 1;
    }
    // epilogue
    if (MODE != 2) {
      short* ob = (short*)outp + (size_t)tile * 64 * CC;
#pragma unroll
      for (int wi = 0; wi < 3; ++wi) {
        int o = w * 48 + wi * 16 + lrow;
#pragma unroll
        for (int ai = 0; ai < 4; ++ai)
#pragma unroll
          for (int r = 0; r < 4; ++r) {
            int p = ai * 16 + lhi * 4 + r;
            float v = acc[ai][wi][r] + bw0[wi];
            if (MODE == 1) v = geluf(v);
            ob[(size_t)p * CC + o] = f2bf(v);
          }
      }
    } else {
      int b = tile / 49, hw0 = (tile - b * 49) * 64;
      float* ob = (float*)outp + (size_t)b * CC * HW + hw0;
#pragma unroll
      for (int wi = 0; wi < 3; ++wi)
#pragma unroll
        for (int r = 0; r < 4; ++r) {
          int o = w * 48 + wi * 16 + lhi * 4 + r;
#pragma unroll
          for (int ai = 0; ai < 4; ++ai)
            ob[(size_t)o * HW + ai * 16 + lrow] = acc[ai][wi][r] + bw2[wi][r];
        }
    }
    tile = tnext;
  }
}

extern "C" void kernel_launch(void* const* d_in, const int* in_sizes, int n_in,
                              void* d_out, int out_size, void* d_ws, size_t ws_size,
                              hipStream_t stream) {
  const float* x     = (const float*)d_in[0];
  const float* cpe_w = (const float*)d_in[1];
  const float* cpe_b = (const float*)d_in[2];
  const float* fc1_w = (const float*)d_in[3];
  const float* fc1_b = (const float*)d_in[4];
  const float* bn1_g = (const float*)d_in[5];
  const float* bn1_b = (const float*)d_in[6];
  const float* bn1_m = (const float*)d_in[7];
  const float* bn1_v = (const float*)d_in[8];
  const float* gc_w  = (const float*)d_in[9];
  const float* gc_b  = (const float*)d_in[10];
  const float* bng_g = (const float*)d_in[11];
  const float* bng_b = (const float*)d_in[12];
  const float* bng_m = (const float*)d_in[13];
  const float* bng_v = (const float*)d_in[14];
  const float* fc2_w = (const float*)d_in[15];
  const float* fc2_b = (const float*)d_in[16];
  const float* bn2_g = (const float*)d_in[17];
  const float* bn2_b = (const float*)d_in[18];
  const float* bn2_m = (const float*)d_in[19];
  const float* bn2_v = (const float*)d_in[20];

  if (ws_size < 77594624) return;
  char* ws = (char*)d_ws;
  __hip_bfloat16* W1f = (__hip_bfloat16*)(ws);
  __hip_bfloat16* Wgf = (__hip_bfloat16*)(ws + 73728);
  __hip_bfloat16* W2f = (__hip_bfloat16*)(ws + 221184);
  float* b1f = (float*)(ws + 294912);
  float* bgf = (float*)(ws + 295680);
  float* b2f = (float*)(ws + 296448);
  __hip_bfloat16* y0  = (__hip_bfloat16*)(ws + 524288);       // pixel-major; reused as y2
  __hip_bfloat16* xjb = (__hip_bfloat16*)(ws + 39059456);
  __hip_bfloat16* y1  = (__hip_bfloat16*)d_out;               // d_out as bf16 scratch
  float* out = (float*)d_out;

  fold_kernel<<<576, 256, 0, stream>>>(fc1_w, fc1_b, bn1_g, bn1_b, bn1_m, bn1_v,
      gc_w, gc_b, bng_g, bng_b, bng_m, bng_v, fc2_w, fc2_b, bn2_g, bn2_b, bn2_m, bn2_v,
      W1f, Wgf, W2f, b1f, bgf, b2f);
  dwconv_kernel<<<NB * 12 * 7, 256, 0, stream>>>(x, cpe_w, cpe_b, y0);
  gemm_kernel<1, 0><<<512, 256, 0, stream>>>(y0, nullptr, W1f, b1f, y1);
  xj_kernel<<<2048, 256, 0, stream>>>(y1, xjb);
  gemm_kernel<2, 1><<<512, 256, 0, stream>>>(y1, xjb, Wgf, bgf, y0);
  gemm_kernel<1, 2><<<512, 256, 0, stream>>>(y0, nullptr, W2f, b2f, out);
}

// Round 7
// 200.007 us; speedup vs baseline: 1.7147x; 1.0350x over previous
//
#include <hip/hip_runtime.h>
#include <hip/hip_bf16.h>

// Grapher block: RepCPE(dw7x7+res) -> fc1+BN -> MRConv4d(K=2) -> gc(2C->C)+BN+GELU -> fc2+BN
// B=32, C=192, H=W=56. d_in/d_out FLOAT32; intermediates bf16.
//
//   fold:   BN-fold weights -> W1f[192][192], Wgf[192][384], W2f[192][192] (bf16), biases fp32
//   dwconv: v6 - (b,16ch,8rows) blocks, 30.6KB LDS, kh-outer loop with 7+7 live weights
//           (software-pipelined), residual via wr[3]+=1 at kh==3, direct 32B-chunk stores
//   gemm*:  weight-stationary (48-o slice per wave in regs), grid-stride over 64-px tiles,
//           2-phase double-buffered LDS staging, XOR-swizzled
//   gemm1:  y1 = y0*W1f^T  (D[p][o]) -> y1 bf16 pm (d_out scratch)
//   xj:     max-relative 4 rolls -> xjb bf16 pm
//   gemm2:  y2 = GELU([y1|xj]*Wgf) (2 chunks) -> y2 bf16 pm
//   gemm3:  out = y2*W2f^T (swapped ops, D[o][p]) -> d_out f32 channel-major

#define CC   192
#define HW   3136
#define NB   32

using short8 = __attribute__((ext_vector_type(8))) short;
using f32x4  = __attribute__((ext_vector_type(4))) float;

__device__ __forceinline__ float bf2f(short s) {
  union { unsigned u; float f; } x; x.u = ((unsigned)(unsigned short)s) << 16; return x.f;
}
__device__ __forceinline__ short f2bf(float f) {
  __hip_bfloat16 h = __float2bfloat16(f);
  return *reinterpret_cast<short*>(&h);
}
__device__ __forceinline__ float geluf(float v) {
  return 0.5f * v * (1.0f + erff(v * 0.70710678118654752f));
}

// ---------------- fold: BN into weights/bias ----------------
__global__ void __launch_bounds__(256) fold_kernel(
    const float* __restrict__ fc1_w, const float* __restrict__ fc1_b,
    const float* __restrict__ bn1_g, const float* __restrict__ bn1_b,
    const float* __restrict__ bn1_m, const float* __restrict__ bn1_v,
    const float* __restrict__ gc_w,  const float* __restrict__ gc_b,
    const float* __restrict__ bng_g, const float* __restrict__ bng_b,
    const float* __restrict__ bng_m, const float* __restrict__ bng_v,
    const float* __restrict__ fc2_w, const float* __restrict__ fc2_b,
    const float* __restrict__ bn2_g, const float* __restrict__ bn2_b,
    const float* __restrict__ bn2_m, const float* __restrict__ bn2_v,
    __hip_bfloat16* __restrict__ W1f, __hip_bfloat16* __restrict__ Wgf, __hip_bfloat16* __restrict__ W2f,
    float* __restrict__ b1f, float* __restrict__ bgf, float* __restrict__ b2f) {
  int gt = blockIdx.x * 256 + threadIdx.x;
  if (gt < 3 * CC) {
    int which = gt / CC, o = gt - which * CC;
    const float *G, *Bt, *M, *V, *Bi; float* dst;
    if (which == 0)      { G = bn1_g; Bt = bn1_b; M = bn1_m; V = bn1_v; Bi = fc1_b; dst = b1f; }
    else if (which == 1) { G = bng_g; Bt = bng_b; M = bng_m; V = bng_v; Bi = gc_b;  dst = bgf; }
    else                 { G = bn2_g; Bt = bn2_b; M = bn2_m; V = bn2_v; Bi = fc2_b; dst = b2f; }
    float inv = G[o] * rsqrtf(V[o] + 1e-5f);
    dst[o] = Bi[o] * inv + Bt[o] - M[o] * inv;
  }
  int i = gt;
  if (i < CC * CC) {
    int o = i / CC;
    float inv = bn1_g[o] * rsqrtf(bn1_v[o] + 1e-5f);
    W1f[i] = __float2bfloat16(fc1_w[i] * inv);
  } else if (i < CC * CC + CC * 2 * CC) {
    int j = i - CC * CC; int o = j / (2 * CC);
    float inv = bng_g[o] * rsqrtf(bng_v[o] + 1e-5f);
    Wgf[j] = __float2bfloat16(gc_w[j] * inv);
  } else if (i < CC * CC * 4) {
    int j = i - CC * CC * 3; int o = j / CC;
    float inv = bn2_g[o] * rsqrtf(bn2_v[o] + 1e-5f);
    W2f[j] = __float2bfloat16(fc2_w[j] * inv);
  }
}

// ---------------- dw 7x7 + bias + residual -> PIXEL-MAJOR bf16 (v6) ----------------
// block: (b, cg of 16 ch, rs of 8 rows). LDS in_t[16 c][14 r][68 col] bf16, c-stride 956.
// thread: c = t&15, g = t>>4 (<14): cgx = g%7 owns 8 cols, rh = g/7 owns 4 rows.
// kh-outer loop: only 7(+7 prefetch) weights live -> wreg stays in registers.
// Residual: wr[3] += 1 at kh==3 (center tap). Direct 32B-chunk global stores.
#define CSTR 956
__global__ void __launch_bounds__(256, 4) dwconv_kernel(
    const float* __restrict__ x, const float* __restrict__ cw,
    const float* __restrict__ cb, __hip_bfloat16* __restrict__ y0pm) {
  __shared__ short in_t[16 * CSTR];            // 30592 B
  const int t = threadIdx.x;
  int bb = blockIdx.x;
  const int rs = bb % 7;  bb /= 7;
  const int cg = bb % 12; bb /= 12;
  const int b  = bb;
  const int h0 = rs * 8;

  for (int i = t; i < 16 * CSTR / 8; i += 256) ((int4*)in_t)[i] = int4{0, 0, 0, 0};
  __syncthreads();

  // stage rows h0-3 .. h0+10 (14 rows), 16 channels, bf16
  for (int it = t; it < 16 * 14 * 14; it += 256) {
    int w4 = it % 14, rr = (it / 14) % 14, c = it / 196;
    int gh = h0 - 3 + rr;
    if (gh >= 0 && gh < 56) {
      float4 v = *(const float4*)(x + ((size_t)(b * CC + cg * 16 + c) * 56 + gh) * 56 + w4 * 4);
      short4 s4 = { f2bf(v.x), f2bf(v.y), f2bf(v.z), f2bf(v.w) };
      *(short4*)(in_t + c * CSTR + rr * 68 + 4 + w4 * 4) = s4;
    }
  }
  __syncthreads();

  const int c = t & 15, g = t >> 4;
  const int cgx = g % 7, rh = g / 7;           // g<14 active
  if (g < 14) {
    const float* wp = cw + (cg * 16 + c) * 49;
    const float bias = cb[cg * 16 + c];
    const short* base = in_t + c * CSTR + rh * 4 * 68 + cgx * 8;
    float acc[4][8] = {};
    float wr[7], wn[7];
#pragma unroll
    for (int i = 0; i < 7; ++i) wr[i] = wp[i];
#pragma unroll
    for (int kh = 0; kh < 7; ++kh) {
      if (kh < 6) {
#pragma unroll
        for (int i = 0; i < 7; ++i) wn[i] = wp[(kh + 1) * 7 + i];
      }
      if (kh == 3) wr[3] += 1.0f;              // residual = center tap + 1
#pragma unroll
      for (int r = 0; r < 4; ++r) {
        const short* rp = base + (r + kh) * 68;
        int2 q0 = *(const int2*)(rp);
        int2 q1 = *(const int2*)(rp + 4);
        int2 q2 = *(const int2*)(rp + 8);
        int2 q3 = *(const int2*)(rp + 12);
        int dw[8] = { q0.x, q0.y, q1.x, q1.y, q2.x, q2.y, q3.x, q3.y };
        float v[16];
#pragma unroll
        for (int q = 0; q < 8; ++q) {
          union { int i; float f; } lo, hi;
          lo.i = dw[q] << 16; hi.i = dw[q] & 0xffff0000;
          v[q * 2] = lo.f; v[q * 2 + 1] = hi.f;
        }
#pragma unroll
        for (int kw = 0; kw < 7; ++kw) {
          float wv = wr[kw];
#pragma unroll
          for (int ww = 0; ww < 8; ++ww)
            acc[r][ww] = fmaf(wv, v[ww + kw + 1], acc[r][ww]);
        }
      }
#pragma unroll
      for (int i = 0; i < 7; ++i) wr[i] = wn[i];
    }
    // direct pixel-major stores: 16 c-lanes = one aligned 32B chunk
    short* dst = (short*)y0pm + ((size_t)b * HW + (size_t)(h0 + rh * 4) * 56 + cgx * 8) * CC
                 + cg * 16 + c;
#pragma unroll
    for (int r = 0; r < 4; ++r)
#pragma unroll
      for (int ww = 0; ww < 8; ++ww)
        dst[(size_t)(r * 56 + ww) * CC] = f2bf(acc[r][ww] + bias);
  }
}

// ---------------- MRConv4d: x_j = relu(max(4 rolled) - center), pixel-major bf16 ----------------
__global__ void __launch_bounds__(256) xj_kernel(const __hip_bfloat16* __restrict__ y1,
                                                 __hip_bfloat16* __restrict__ xjb) {
  const int total = NB * HW * 24;
  const short* base = (const short*)y1;
  for (int idx = blockIdx.x * 256 + threadIdx.x; idx < total; idx += gridDim.x * 256) {
    int cg = idx % 24;
    int row = idx / 24;
    int b = row / HW, hw = row - b * HW;
    int h = hw / 56, wv = hw - h * 56;
    int hp = (h >= 54) ? h - 54 : h + 2;
    int hm = (h < 2) ? h + 54 : h - 2;
    int wpp = (wv >= 54) ? wv - 54 : wv + 2;
    int wmm = (wv < 2) ? wv + 54 : wv - 2;
    size_t rb = (size_t)b * HW;
    int co = cg * 8;
    short8 c0 = *(const short8*)(base + (rb + hw) * CC + co);
    short8 n1 = *(const short8*)(base + (rb + hp * 56 + wv) * CC + co);
    short8 n2 = *(const short8*)(base + (rb + hm * 56 + wv) * CC + co);
    short8 n3 = *(const short8*)(base + (rb + h * 56 + wpp) * CC + co);
    short8 n4 = *(const short8*)(base + (rb + h * 56 + wmm) * CC + co);
    short8 res;
#pragma unroll
    for (int j = 0; j < 8; ++j) {
      float m = fmaxf(fmaxf(bf2f(n1[j]), bf2f(n2[j])), fmaxf(bf2f(n3[j]), bf2f(n4[j])));
      m = fmaxf(m - bf2f(c0[j]), 0.0f);
      res[j] = f2bf(m);
    }
    *(short8*)((short*)xjb + (rb + hw) * CC + co) = res;
  }
}

// ---------------- gemm v3: weight-stationary, grid-stride, 2-phase dbuf ----------------
__device__ __forceinline__ void stage_tile(char* dst, const char* src,
                                           const int* sp, const int* sq) {
#pragma unroll
  for (int j = 0; j < 6; ++j) {
    short8 v = *(const short8*)(src + (size_t)sp[j] * 384 + sq[j]);
    *(short8*)(dst + sp[j] * 384 + (sq[j] ^ ((sp[j] & 7) << 4))) = v;
  }
}

template<int K_IN>
__device__ __forceinline__ void wload(short8 (&wreg)[6][3], const short* Wf,
                                      int w, int lrow, int lhi, int koff) {
#pragma unroll
  for (int kk = 0; kk < 6; ++kk)
#pragma unroll
    for (int wi = 0; wi < 3; ++wi) {
      int o = w * 48 + wi * 16 + lrow;
      wreg[kk][wi] = *(const short8*)(Wf + (size_t)o * K_IN + koff + kk * 32 + lhi * 8);
    }
}

// MODE 0: bf16 pm out; MODE 1: GELU bf16 pm out; MODE 2: swapped -> f32 channel-major
template<int NCHUNK, int MODE>
__global__ void __launch_bounds__(256, 2) gemm_kernel(
    const __hip_bfloat16* __restrict__ actA, const __hip_bfloat16* __restrict__ actB,
    const __hip_bfloat16* __restrict__ Wf, const float* __restrict__ bfv,
    void* __restrict__ outp) {
  __shared__ char smem[2][24576];
  const int t = threadIdx.x;
  const int lane = t & 63, w = t >> 6;
  const int lrow = lane & 15, lhi = lane >> 4;
  constexpr int K_IN = NCHUNK * 192;
  constexpr int NT = NB * 49;          // 1568 pixel tiles of 64

  int sp[6], sq[6];
#pragma unroll
  for (int j = 0; j < 6; ++j) {
    int idx = j * 256 + t;
    sp[j] = idx / 24;
    sq[j] = (idx - sp[j] * 24) * 16;
  }

  float bw0[3];
  float bw2[3][4];
  if (MODE != 2) {
#pragma unroll
    for (int wi = 0; wi < 3; ++wi) bw0[wi] = bfv[w * 48 + wi * 16 + lrow];
  } else {
#pragma unroll
    for (int wi = 0; wi < 3; ++wi)
#pragma unroll
      for (int r = 0; r < 4; ++r) bw2[wi][r] = bfv[w * 48 + wi * 16 + lhi * 4 + r];
  }

  short8 wreg[6][3];
  if (NCHUNK == 1) wload<K_IN>(wreg, (const short*)Wf, w, lrow, lhi, 0);

  const int step = gridDim.x;
  int tile = blockIdx.x;
  stage_tile(smem[0], (const char*)actA + (size_t)tile * 24576, sp, sq);
  __syncthreads();
  int cur = 0;

  while (tile < NT) {
    const int tnext = tile + step;
    f32x4 acc[4][3] = {};
#pragma unroll
    for (int c = 0; c < NCHUNK; ++c) {
      // issue next stage into the other buffer (overlaps with compute below)
      if (c + 1 < NCHUNK)
        stage_tile(smem[cur ^ 1], (const char*)actB + (size_t)tile * 24576, sp, sq);
      else if (tnext < NT)
        stage_tile(smem[cur ^ 1], (const char*)actA + (size_t)tnext * 24576, sp, sq);
      if (NCHUNK > 1) wload<K_IN>(wreg, (const short*)Wf, w, lrow, lhi, c * 192);
#pragma unroll
      for (int kk = 0; kk < 6; ++kk) {
        short8 af[4];
#pragma unroll
        for (int ai = 0; ai < 4; ++ai) {
          int p = ai * 16 + lrow;
          af[ai] = *(const short8*)(smem[cur] + p * 384 + ((kk * 64 + lhi * 16) ^ ((p & 7) << 4)));
        }
#pragma unroll
        for (int ai = 0; ai < 4; ++ai)
#pragma unroll
          for (int wi = 0; wi < 3; ++wi)
            acc[ai][wi] = (MODE == 2)
                ? __builtin_amdgcn_mfma_f32_16x16x32_bf16(wreg[kk][wi], af[ai], acc[ai][wi], 0, 0, 0)
                : __builtin_amdgcn_mfma_f32_16x16x32_bf16(af[ai], wreg[kk][wi], acc[ai][wi], 0, 0, 0);
      }
      __syncthreads();
      cur ^= 1;
    }
    // epilogue
    if (MODE != 2) {
      short* ob = (short*)outp + (size_t)tile * 64 * CC;
#pragma unroll
      for (int wi = 0; wi < 3; ++wi) {
        int o = w * 48 + wi * 16 + lrow;
#pragma unroll
        for (int ai = 0; ai < 4; ++ai)
#pragma unroll
          for (int r = 0; r < 4; ++r) {
            int p = ai * 16 + lhi * 4 + r;
            float v = acc[ai][wi][r] + bw0[wi];
            if (MODE == 1) v = geluf(v);
            ob[(size_t)p * CC + o] = f2bf(v);
          }
      }
    } else {
      int b = tile / 49, hw0 = (tile - b * 49) * 64;
      float* ob = (float*)outp + (size_t)b * CC * HW + hw0;
#pragma unroll
      for (int wi = 0; wi < 3; ++wi)
#pragma unroll
        for (int r = 0; r < 4; ++r) {
          int o = w * 48 + wi * 16 + lhi * 4 + r;
#pragma unroll
          for (int ai = 0; ai < 4; ++ai)
            ob[(size_t)o * HW + ai * 16 + lrow] = acc[ai][wi][r] + bw2[wi][r];
        }
    }
    tile = tnext;
  }
}

extern "C" void kernel_launch(void* const* d_in, const int* in_sizes, int n_in,
                              void* d_out, int out_size, void* d_ws, size_t ws_size,
                              hipStream_t stream) {
  const float* x     = (const float*)d_in[0];
  const float* cpe_w = (const float*)d_in[1];
  const float* cpe_b = (const float*)d_in[2];
  const float* fc1_w = (const float*)d_in[3];
  const float* fc1_b = (const float*)d_in[4];
  const float* bn1_g = (const float*)d_in[5];
  const float* bn1_b = (const float*)d_in[6];
  const float* bn1_m = (const float*)d_in[7];
  const float* bn1_v = (const float*)d_in[8];
  const float* gc_w  = (const float*)d_in[9];
  const float* gc_b  = (const float*)d_in[10];
  const float* bng_g = (const float*)d_in[11];
  const float* bng_b = (const float*)d_in[12];
  const float* bng_m = (const float*)d_in[13];
  const float* bng_v = (const float*)d_in[14];
  const float* fc2_w = (const float*)d_in[15];
  const float* fc2_b = (const float*)d_in[16];
  const float* bn2_g = (const float*)d_in[17];
  const float* bn2_b = (const float*)d_in[18];
  const float* bn2_m = (const float*)d_in[19];
  const float* bn2_v = (const float*)d_in[20];

  if (ws_size < 77594624) return;
  char* ws = (char*)d_ws;
  __hip_bfloat16* W1f = (__hip_bfloat16*)(ws);
  __hip_bfloat16* Wgf = (__hip_bfloat16*)(ws + 73728);
  __hip_bfloat16* W2f = (__hip_bfloat16*)(ws + 221184);
  float* b1f = (float*)(ws + 294912);
  float* bgf = (float*)(ws + 295680);
  float* b2f = (float*)(ws + 296448);
  __hip_bfloat16* y0  = (__hip_bfloat16*)(ws + 524288);       // pixel-major; reused as y2
  __hip_bfloat16* xjb = (__hip_bfloat16*)(ws + 39059456);
  __hip_bfloat16* y1  = (__hip_bfloat16*)d_out;               // d_out as bf16 scratch
  float* out = (float*)d_out;

  fold_kernel<<<576, 256, 0, stream>>>(fc1_w, fc1_b, bn1_g, bn1_b, bn1_m, bn1_v,
      gc_w, gc_b, bng_g, bng_b, bng_m, bng_v, fc2_w, fc2_b, bn2_g, bn2_b, bn2_m, bn2_v,
      W1f, Wgf, W2f, b1f, bgf, b2f);
  dwconv_kernel<<<NB * 12 * 7, 256, 0, stream>>>(x, cpe_w, cpe_b, y0);
  gemm_kernel<1, 0><<<512, 256, 0, stream>>>(y0, nullptr, W1f, b1f, y1);
  xj_kernel<<<2048, 256, 0, stream>>>(y1, xjb);
  gemm_kernel<2, 1><<<512, 256, 0, stream>>>(y1, xjb, Wgf, bgf, y0);
  gemm_kernel<1, 2><<<512, 256, 0, stream>>>(y0, nullptr, W2f, b2f, out);
}